// Round 6
// baseline (454.857 us; speedup 1.0000x reference)
//
#include <hip/hip_runtime.h>
#include <hip/hip_fp16.h>
#include <cmath>

#define HEADS 4
#define CH 64
#define HC 256
#define NEG 0.2f

typedef __attribute__((ext_vector_type(8))) short short8;
typedef __attribute__((ext_vector_type(4))) float f32x4;
typedef __fp16 half2_t __attribute__((ext_vector_type(2)));

__device__ __forceinline__ float leaky(float v){ return v > 0.f ? v : NEG * v; }

__device__ __forceinline__ short bf16_rne(float f){
    unsigned u = __float_as_uint(f);
    unsigned r = u + 0x7fffu + ((u >> 16) & 1u);
    return (short)(r >> 16);
}
__device__ __forceinline__ float bf16_to_f(short s){
    return __uint_as_float(((unsigned)(unsigned short)s) << 16);
}
__device__ __forceinline__ half2_t bc16(unsigned u){ return __builtin_bit_cast(half2_t, u); }
__device__ __forceinline__ unsigned packh2(float a, float b){
    __half ha = __float2half(a), hb = __float2half(b);   // RNE
    return (unsigned)__builtin_bit_cast(unsigned short, ha)
         | ((unsigned)__builtin_bit_cast(unsigned short, hb) << 16);
}
__device__ __forceinline__ float fd2(unsigned hv, unsigned w, float acc){
    return __builtin_amdgcn_fdot2(bc16(hv), bc16(w), acc, false);
}

// block-wide exclusive scan of one int per thread (256 threads)
__device__ __forceinline__ int block_excl_scan(int v, int* ws4){
    int tid = threadIdx.x, lane = tid & 63, wv = tid >> 6;
    int incl = v;
    #pragma unroll
    for (int off = 1; off < 64; off <<= 1){
        int t = __shfl_up(incl, off);
        if (lane >= off) incl += t;
    }
    if (lane == 63) ws4[wv] = incl;
    __syncthreads();
    int add = 0;
    for (int w = 0; w < wv; ++w) add += ws4[w];
    return incl - v + add;
}

// ---------------- prep (+ edge histogram tail) ----------------

__global__ __launch_bounds__(256) void prep_hist_kernel(
    const float* __restrict__ W1, const float* __restrict__ W2,
    const float* __restrict__ Ws1, const float* __restrict__ bs1,
    const float* __restrict__ donor,
    short* __restrict__ w1hi, short* __restrict__ w2hi,
    short* __restrict__ s1hi, short* __restrict__ s1lo,
    float* __restrict__ d1p,
    const int* __restrict__ ei, int E, int N, int NB, int* __restrict__ bucket_cnt)
{
    if ((int)blockIdx.x < 256){
        int t = blockIdx.x * 256 + threadIdx.x;
        int T = 256 * 256;
        for (int i = t; i < 256 * 40; i += T){                  // W1 bf16: [n=256][k pitch 40], K=27
            int n = i / 40, k = i % 40;
            w1hi[i] = bf16_rne((k < 27) ? W1[(size_t)k * HC + n] : 0.f);
        }
        for (int i = t; i < 256 * 72; i += T){                  // W2 bf16: [n=256][k pitch 72], K=64
            int n = i / 72, k = i % 72;
            w2hi[i] = bf16_rne((k < 64) ? W2[(size_t)k * HC + n] : 0.f);
        }
        for (int i = t; i < 64 * 72; i += T){                   // Ws1 bf16x3 (scorer)
            int n = i / 72, k = i % 72;
            float v = (k < 64) ? Ws1[(size_t)k * 64 + n] : 0.f;
            short hi = bf16_rne(v);
            s1hi[i] = hi; s1lo[i] = bf16_rne(v - bf16_to_f(hi));
        }
        if (t < 64){
            float s = bs1[t];
            for (int k = 0; k < 32; ++k) s = fmaf(donor[k], Ws1[(size_t)(64 + k) * 64 + t], s);
            d1p[t] = s;
        }
    } else {
        __shared__ int lh[256];
        int tid = threadIdx.x;
        int ET = E + N;
        int ebase = ((int)blockIdx.x - 256) * 2048;
        lh[tid] = 0;
        __syncthreads();
        #pragma unroll
        for (int j = 0; j < 8; ++j){
            int e = ebase + j * 256 + tid;
            if (e < ET){
                int d = (e < E) ? ei[E + e] : (e - E);
                atomicAdd(&lh[d >> 8], 1);
            }
        }
        __syncthreads();
        if (tid < NB && lh[tid]) atomicAdd(&bucket_cnt[tid], lh[tid]);
    }
}

// ---------------- coarse scatter (self-scan, packed uint32 pairs) ----------------

__global__ __launch_bounds__(256) void coarse_scatter_kernel(
    const int* __restrict__ ei, int E, int N, int NB,
    const int* __restrict__ bucket_cnt, int* __restrict__ bucket_cursor,
    unsigned* __restrict__ pairs)
{
    __shared__ int ws4[4];
    __shared__ int gbase[256];
    __shared__ int lh[256];
    __shared__ int gb[256];
    int tid = threadIdx.x;
    int ET = E + N;
    {
        int v = (tid < NB) ? bucket_cnt[tid] : 0;
        gbase[tid] = block_excl_scan(v, ws4);
    }
    lh[tid] = 0;
    __syncthreads();
    int ebase = blockIdx.x * 2048;
    int d[8], s[8], r[8];
    #pragma unroll
    for (int j = 0; j < 8; ++j){
        int e = ebase + j * 256 + tid;
        d[j] = -1;
        if (e < ET){
            if (e < E){ s[j] = ei[e]; d[j] = ei[E + e]; } else { s[j] = d[j] = e - E; }
            r[j] = atomicAdd(&lh[d[j] >> 8], 1);
        }
    }
    __syncthreads();
    if (tid < NB && lh[tid]) gb[tid] = gbase[tid] + atomicAdd(&bucket_cursor[tid], lh[tid]);
    __syncthreads();
    #pragma unroll
    for (int j = 0; j < 8; ++j){
        if (d[j] >= 0)
            pairs[gb[d[j] >> 8] + r[j]] = ((unsigned)d[j] << 16) | (unsigned)s[j];
    }
}

// ---------------- fine sort body (self-scan, block-local writes) ----------------

__device__ __forceinline__ void fine_sort_body(
    int b, const unsigned* __restrict__ pairs, const int* __restrict__ bucket_cnt, int NB,
    int* __restrict__ colsrc, int* __restrict__ rowptr, int N, int ET)
{
    __shared__ int ws4f[4];
    __shared__ int sb[257];
    __shared__ int hist[256];
    __shared__ int cur[256];
    int tid = threadIdx.x;
    {
        int v = (tid < NB) ? bucket_cnt[tid] : 0;
        int excl = block_excl_scan(v, ws4f);
        sb[tid] = excl;
        if (tid == 255) sb[256] = excl + v;
    }
    hist[tid] = 0;
    __syncthreads();
    int base = sb[b], endb = sb[b + 1];
    int cnt = endb - base;
    int d0 = b << 8;
    for (int i = tid; i < cnt; i += 256){
        unsigned p = pairs[base + i];
        atomicAdd(&hist[(int)(p >> 16) - d0], 1);
    }
    __syncthreads();
    int v = hist[tid];
    int excl = block_excl_scan(v, ws4f);
    cur[tid] = excl;
    if (d0 + tid < N) rowptr[d0 + tid] = base + excl;
    if (b == 0 && tid == 0) rowptr[N] = ET;
    __syncthreads();
    for (int i = tid; i < cnt; i += 256){
        unsigned p = pairs[base + i];
        int r = atomicAdd(&cur[(int)(p >> 16) - d0], 1);
        colsrc[base + r] = (int)(p & 0xFFFFu);
    }
}

// ---------------- MFMA node transform (device body) ----------------
// X3: bf16x3 A*B split. DIRECT: FIN==64, read A-fragments straight from global.
// h output layout is SLICE-MAJOR: h[8][N][64B] (slice = 64B of the logical
// 512B row). A 128B L2 line then holds 2 NODES of the SAME slice -> XCD-
// resident in aggregate_slice (verified r5: FETCH 241->84MB).

template<int FIN, int KSTEPS, int NT, bool X3, bool DIRECT>
__device__ __forceinline__ void transform_body(
    int bx, int by,
    const float* __restrict__ xin, const short* __restrict__ whi, const short* __restrict__ wlo,
    const float* __restrict__ a_src, const float* __restrict__ a_dst,
    __half* __restrict__ h, float* __restrict__ asrc, float* __restrict__ adst, int N)
{
    constexpr int KP = KSTEPS * 32;
    constexpr int XP = KP + 4;
    constexpr int WP = KP + 8;
    constexpr int NCOL = NT * 16;
    __shared__ float xl[DIRECT ? 8 : 64 * XP];
    __shared__ short wt_hi[NCOL * WP];
    __shared__ short wt_lo[X3 ? NCOL * WP : 8];

    const int tid = threadIdx.x;
    const int n0 = bx * 64;
    const int c0 = by * NCOL;
    const size_t sstr = (size_t)N * 64;

    const int wv = tid >> 6, lane = tid & 63;
    const int quad = lane >> 4, ln = lane & 15;
    const int myrow = wv * 16 + ln;

    float fdir[DIRECT ? KSTEPS * 8 : 1];
    if (DIRECT){
        int n = n0 + myrow;
        #pragma unroll
        for (int ks = 0; ks < KSTEPS; ++ks){
            float4 f0 = make_float4(0.f, 0.f, 0.f, 0.f), f1 = f0;
            if (n < N){
                const float* ap = xin + (size_t)n * FIN + ks * 32 + quad * 8;
                f0 = *(const float4*)ap;
                f1 = *(const float4*)(ap + 4);
            }
            fdir[ks*8+0]=f0.x; fdir[ks*8+1]=f0.y; fdir[ks*8+2]=f0.z; fdir[ks*8+3]=f0.w;
            fdir[ks*8+4]=f1.x; fdir[ks*8+5]=f1.y; fdir[ks*8+6]=f1.z; fdir[ks*8+7]=f1.w;
        }
    } else {
        for (int t = tid; t < 64 * KP; t += 256) {
            int row = t / KP, k = t % KP;
            int n = n0 + row;
            float v = 0.f;
            if (n < N && k < FIN) v = xin[(size_t)n * FIN + k];
            xl[row * XP + k] = v;
        }
    }
    {
        const short8* ghi = (const short8*)(whi + (size_t)c0 * WP);
        short8* lhi = (short8*)wt_hi;
        for (int t = tid; t < NCOL * WP / 8; t += 256) lhi[t] = ghi[t];
        if (X3){
            const short8* glo = (const short8*)(wlo + (size_t)c0 * WP);
            short8* llo = (short8*)wt_lo;
            for (int t = tid; t < NCOL * WP / 8; t += 256) llo[t] = glo[t];
        }
    }
    __syncthreads();

    f32x4 acc[NT];
    #pragma unroll
    for (int i = 0; i < NT; ++i) acc[i] = (f32x4){0.f, 0.f, 0.f, 0.f};

    #pragma unroll
    for (int ks = 0; ks < KSTEPS; ++ks) {
        const int k0 = ks * 32 + quad * 8;
        float fa[8];
        if (DIRECT){
            #pragma unroll
            for (int e = 0; e < 8; ++e) fa[e] = fdir[ks * 8 + e];
        } else {
            const float* ap = xl + myrow * XP + k0;
            float4 f0 = *(const float4*)ap;
            float4 f1 = *(const float4*)(ap + 4);
            fa[0]=f0.x; fa[1]=f0.y; fa[2]=f0.z; fa[3]=f0.w;
            fa[4]=f1.x; fa[5]=f1.y; fa[6]=f1.z; fa[7]=f1.w;
        }
        short8 ahi, alo;
        #pragma unroll
        for (int e = 0; e < 8; ++e) {
            short hi = bf16_rne(fa[e]);
            ahi[e] = hi;
            alo[e] = bf16_rne(fa[e] - bf16_to_f(hi));
        }
        #pragma unroll
        for (int nt = 0; nt < NT; ++nt) {
            short8 bhi = *(const short8*)(wt_hi + (nt * 16 + ln) * WP + k0);
            acc[nt] = __builtin_amdgcn_mfma_f32_16x16x32_bf16(ahi, bhi, acc[nt], 0, 0, 0);
            acc[nt] = __builtin_amdgcn_mfma_f32_16x16x32_bf16(alo, bhi, acc[nt], 0, 0, 0);
            if (X3){
                short8 blo = *(const short8*)(wt_lo + (nt * 16 + ln) * WP + k0);
                acc[nt] = __builtin_amdgcn_mfma_f32_16x16x32_bf16(ahi, blo, acc[nt], 0, 0, 0);
            }
        }
    }

    #pragma unroll
    for (int r = 0; r < 4; ++r) {
        int n = n0 + wv * 16 + quad * 4 + r;
        if (n < N) {
            if (NT == 16) {
                // logical byte b = (q*16+ln)*8 -> slice b>>6 = q*2+(ln>>3), within-slice (ln&7)*8
                #pragma unroll
                for (int q = 0; q < 4; ++q) {
                    uint2 u;
                    u.x = packh2(acc[q][r],     acc[q + 4][r]);
                    u.y = packh2(acc[q + 8][r], acc[q + 12][r]);
                    *(uint2*)((char*)h + (size_t)(q * 2 + (ln >> 3)) * sstr
                              + (size_t)n * 64 + (ln & 7) * 8) = u;
                }
            } else {
                #pragma unroll
                for (int q = 0; q < 4; ++q) {
                    unsigned u = packh2(acc[q][r], acc[q + 4][r]);
                    int b = (q * 16 + ln) * 8 + ((c0 >> 6) << 1);
                    *(unsigned*)((char*)h + (size_t)(b >> 6) * sstr
                                 + (size_t)n * 64 + (b & 63)) = u;
                }
            }
        }
    }

    float aS[NT], aD[NT];
    #pragma unroll
    for (int nt = 0; nt < NT; ++nt) {
        aS[nt] = a_src[c0 + nt * 16 + ln];
        aD[nt] = a_dst[c0 + nt * 16 + ln];
    }
    #pragma unroll
    for (int hl = 0; hl < NT / 4; ++hl) {
        #pragma unroll
        for (int r = 0; r < 4; ++r) {
            float ps = 0.f, pd = 0.f;
            #pragma unroll
            for (int i = 0; i < 4; ++i) {
                ps = fmaf(acc[hl * 4 + i][r], aS[hl * 4 + i], ps);
                pd = fmaf(acc[hl * 4 + i][r], aD[hl * 4 + i], pd);
            }
            #pragma unroll
            for (int off = 1; off < 16; off <<= 1) {
                ps += __shfl_xor(ps, off);
                pd += __shfl_xor(pd, off);
            }
            if (ln == 0) {
                int n = n0 + wv * 16 + quad * 4 + r;
                if (n < N) {
                    int hg = c0 / 64 + hl;
                    asrc[n * 4 + hg] = ps;
                    adst[n * 4 + hg] = pd;
                }
            }
        }
    }
}

// transform1 (bf16x2, LDS-staged x: FIN=27) fused with fine-sort tail blocks
__global__ __launch_bounds__(256) void transform1_fine_kernel(
    const float* __restrict__ xin, const short* __restrict__ whi,
    const float* __restrict__ a_src, const float* __restrict__ a_dst,
    __half* __restrict__ h, float* __restrict__ asrc, float* __restrict__ adst, int N,
    int nblk, const unsigned* __restrict__ pairs, const int* __restrict__ bucket_cnt, int NB,
    int* __restrict__ colsrc, int* __restrict__ rowptr, int ET)
{
    if ((int)blockIdx.x < nblk) {
        transform_body<27, 1, 16, false, false>(blockIdx.x, 0, xin, whi, nullptr,
                                                a_src, a_dst, h, asrc, adst, N);
    } else {
        fine_sort_body(blockIdx.x - nblk, pairs, bucket_cnt, NB, colsrc, rowptr, N, ET);
    }
}

// transform2: NT=16 single pass, bf16x2, DIRECT global A reads (36.9 KB LDS)
__global__ __launch_bounds__(256) void transform2_kernel(
    const float* __restrict__ xin, const short* __restrict__ whi,
    const float* __restrict__ a_src, const float* __restrict__ a_dst,
    __half* __restrict__ h, float* __restrict__ asrc, float* __restrict__ adst, int N)
{
    transform_body<64, 2, 16, false, true>(blockIdx.x, 0, xin, whi, nullptr,
                                           a_src, a_dst, h, asrc, adst, N);
}

// ---------------- edge softmax weights (per-edge alpha, packed half x4) ----------------

__global__ __launch_bounds__(256) void edge_alpha_kernel(
    const int* __restrict__ rowptr, const int* __restrict__ colsrc,
    const float* __restrict__ asrc, const float* __restrict__ adst,
    uint2* __restrict__ alpha, int N)
{
    int tid = threadIdx.x;
    int grp = tid >> 5;
    int lane32 = tid & 31;
    int n = blockIdx.x * 8 + grp;
    if (n >= N) return;
    int start = rowptr[n], end = rowptr[n + 1];
    int deg = end - start;
    const float4 ad = *(const float4*)(adst + (size_t)n * 4);

    float e0 = -1e30f, e1 = -1e30f, e2 = -1e30f, e3 = -1e30f;
    bool v0 = lane32 < deg;
    if (v0){
        int s = colsrc[start + lane32];
        float4 as = *(const float4*)(asrc + (size_t)s * 4);
        e0 = leaky(as.x + ad.x); e1 = leaky(as.y + ad.y);
        e2 = leaky(as.z + ad.z); e3 = leaky(as.w + ad.w);
    }

    if (deg <= 32){
        float m0 = e0, m1 = e1, m2 = e2, m3 = e3;
        #pragma unroll
        for (int off = 1; off < 32; off <<= 1){
            m0 = fmaxf(m0, __shfl_xor(m0, off));
            m1 = fmaxf(m1, __shfl_xor(m1, off));
            m2 = fmaxf(m2, __shfl_xor(m2, off));
            m3 = fmaxf(m3, __shfl_xor(m3, off));
        }
        float p0 = __expf(e0 - m0);
        float p1 = __expf(e1 - m1);
        float p2 = __expf(e2 - m2);
        float p3 = __expf(e3 - m3);
        float t0 = p0, t1 = p1, t2 = p2, t3 = p3;
        #pragma unroll
        for (int off = 1; off < 32; off <<= 1){
            t0 += __shfl_xor(t0, off);
            t1 += __shfl_xor(t1, off);
            t2 += __shfl_xor(t2, off);
            t3 += __shfl_xor(t3, off);
        }
        if (v0){
            half2_t q01 = __builtin_amdgcn_cvt_pkrtz(p0 / t0, p1 / t1);
            half2_t q23 = __builtin_amdgcn_cvt_pkrtz(p2 / t2, p3 / t3);
            uint2 w;
            w.x = __builtin_bit_cast(unsigned, q01);
            w.y = __builtin_bit_cast(unsigned, q23);
            alpha[start + lane32] = w;
        }
    } else {
        float m0 = e0, m1 = e1, m2 = e2, m3 = e3;
        float t0 = v0 ? 1.f : 0.f, t1 = t0, t2 = t0, t3 = t0;
        for (int i = start + 32 + lane32; i < end; i += 32){
            int s = colsrc[i];
            float4 as = *(const float4*)(asrc + (size_t)s * 4);
            float e, nm;
            e = leaky(as.x + ad.x); nm = fmaxf(m0, e); t0 = t0 * __expf(m0 - nm) + __expf(e - nm); m0 = nm;
            e = leaky(as.y + ad.y); nm = fmaxf(m1, e); t1 = t1 * __expf(m1 - nm) + __expf(e - nm); m1 = nm;
            e = leaky(as.z + ad.z); nm = fmaxf(m2, e); t2 = t2 * __expf(m2 - nm) + __expf(e - nm); m2 = nm;
            e = leaky(as.w + ad.w); nm = fmaxf(m3, e); t3 = t3 * __expf(m3 - nm) + __expf(e - nm); m3 = nm;
        }
        #pragma unroll
        for (int off = 1; off < 32; off <<= 1){
            float om, os, nm;
            om = __shfl_xor(m0, off); os = __shfl_xor(t0, off);
            nm = fmaxf(m0, om); t0 = t0 * __expf(m0 - nm) + os * __expf(om - nm); m0 = nm;
            om = __shfl_xor(m1, off); os = __shfl_xor(t1, off);
            nm = fmaxf(m1, om); t1 = t1 * __expf(m1 - nm) + os * __expf(om - nm); m1 = nm;
            om = __shfl_xor(m2, off); os = __shfl_xor(t2, off);
            nm = fmaxf(m2, om); t2 = t2 * __expf(m2 - nm) + os * __expf(om - nm); m2 = nm;
            om = __shfl_xor(m3, off); os = __shfl_xor(t3, off);
            nm = fmaxf(m3, om); t3 = t3 * __expf(m3 - nm) + os * __expf(om - nm); m3 = nm;
        }
        float i0 = 1.f / t0, i1 = 1.f / t1, i2 = 1.f / t2, i3 = 1.f / t3;

        bool first = true;
        for (int base = start; base < end; base += 32){
            int cnt = end - base; if (cnt > 32) cnt = 32;
            float w0 = 0.f, w1 = 0.f, w2 = 0.f, w3 = 0.f;
            if (first){
                w0 = __expf(e0 - m0) * i0; w1 = __expf(e1 - m1) * i1;
                w2 = __expf(e2 - m2) * i2; w3 = __expf(e3 - m3) * i3;
            } else if (lane32 < cnt){
                int s = colsrc[base + lane32];
                float4 as = *(const float4*)(asrc + (size_t)s * 4);
                w0 = __expf(leaky(as.x + ad.x) - m0) * i0;
                w1 = __expf(leaky(as.y + ad.y) - m1) * i1;
                w2 = __expf(leaky(as.z + ad.z) - m2) * i2;
                w3 = __expf(leaky(as.w + ad.w) - m3) * i3;
            }
            first = false;
            if (lane32 < cnt){
                half2_t q01 = __builtin_amdgcn_cvt_pkrtz(w0, w1);
                half2_t q23 = __builtin_amdgcn_cvt_pkrtz(w2, w3);
                uint2 w;
                w.x = __builtin_bit_cast(unsigned, q01);
                w.y = __builtin_bit_cast(unsigned, q23);
                alpha[base + lane32] = w;
            }
        }
    }
}

// ---------------- channel-sliced aggregation (slice-major h, width-parallel) ----------------
// r5 postmortem: FETCH 84MB confirmed L2-resident h, but per-quad SERIAL edge
// walk was latency-bound (VALUBusy 12%, 0.96TB/s). v2: a 32-lane half-wave
// processes 8 EDGES of one node concurrently (group g = edge, quarter q =
// 16B of the 64B slice chunk) -> 8 independent gathers in flight per issue,
// latency hidden by width. Cross-group shfl_xor(4/8/16) reduction at the end.
// No deg<=32 special case needed. Streams stay nontemporal (h-slice stays
// resident); invalid tail edges neutralized via alpha=0 (no divergence).

__global__ __launch_bounds__(256) void aggregate_slice_kernel(
    const int* __restrict__ rowptr, const int* __restrict__ colsrc,
    const uint2* __restrict__ alpha, const __half* __restrict__ h,
    const float* __restrict__ bias, float* __restrict__ hout, int N)
{
    int tid = threadIdx.x;
    int slice = blockIdx.x & 7;
    int chunk = blockIdx.x >> 3;
    int lane32 = tid & 31;
    int g = lane32 >> 2;            // edge group 0..7
    int q = lane32 & 3;             // 16B quarter of the 64B slice chunk
    int n = chunk * 8 + (tid >> 5);
    if (n >= N) return;
    int start = rowptr[n], end = rowptr[n + 1];
    const char* hs = (const char*)h + (size_t)slice * ((size_t)N * 64);
    const int sb = q * 16;

    float accA = 0.f, accB = 0.f;
    for (int base = start; base < end; base += 8){
        int idx = base + g;
        bool valid = idx < end;
        int ci = valid ? idx : (end - 1);
        int src = __builtin_nontemporal_load(colsrc + ci);
        unsigned long long av =
            __builtin_nontemporal_load((const unsigned long long*)(alpha + ci));
        unsigned wA = (unsigned)av, wB = (unsigned)(av >> 32);
        if (!valid){ wA = 0u; wB = 0u; }   // zero weight, clamped row is real data
        uint4 hv = *(const uint4*)(hs + (size_t)src * 64 + sb);
        accA = fd2(hv.x, wA, accA); accA = fd2(hv.y, wB, accA);
        accB = fd2(hv.z, wA, accB); accB = fd2(hv.w, wB, accB);
    }
    #pragma unroll
    for (int off = 4; off < 32; off <<= 1){
        accA += __shfl_xor(accA, off);
        accB += __shfl_xor(accB, off);
    }
    if (g == 0){
        int c = slice * 8 + q * 2;
        float2 bv = *(const float2*)(bias + c);
        float oA = accA * 0.25f + bv.x;
        float oB = accB * 0.25f + bv.y;
        oA = (oA > 0.f) ? oA : expm1f(oA);
        oB = (oB > 0.f) ? oB : expm1f(oB);
        float2 o2 = make_float2(oA, oB);
        __builtin_nontemporal_store(__builtin_bit_cast(double, o2),
                                    (double*)(hout + (size_t)n * CH + c));
    }
}

// ---------------- scorer: MFMA (bf16x3), DIRECT global A reads ----------------

__global__ __launch_bounds__(256) void scorer_mfma_kernel(
    const float* __restrict__ h2, const short* __restrict__ s1hi, const short* __restrict__ s1lo,
    const float* __restrict__ d1p, const float* __restrict__ Ws2, const float* __restrict__ bs2,
    float* __restrict__ out, int N)
{
    constexpr int WP = 72;
    __shared__ short whi[64 * WP];
    __shared__ short wlo[64 * WP];
    const int tid = threadIdx.x;
    const int n0 = blockIdx.x * 64;

    const int wv = tid >> 6, lane = tid & 63;
    const int quad = lane >> 4, ln = lane & 15;
    const int myrow = wv * 16 + ln;
    const int nme = n0 + myrow;

    float fdir[16];
    #pragma unroll
    for (int ks = 0; ks < 2; ++ks){
        float4 f0 = make_float4(0.f, 0.f, 0.f, 0.f), f1 = f0;
        if (nme < N){
            const float* ap = h2 + (size_t)nme * 64 + ks * 32 + quad * 8;
            f0 = *(const float4*)ap;
            f1 = *(const float4*)(ap + 4);
        }
        fdir[ks*8+0]=f0.x; fdir[ks*8+1]=f0.y; fdir[ks*8+2]=f0.z; fdir[ks*8+3]=f0.w;
        fdir[ks*8+4]=f1.x; fdir[ks*8+5]=f1.y; fdir[ks*8+6]=f1.z; fdir[ks*8+7]=f1.w;
    }
    {
        const short8* ghi = (const short8*)s1hi;
        const short8* glo = (const short8*)s1lo;
        short8* lhi = (short8*)whi;
        short8* llo = (short8*)wlo;
        for (int t = tid; t < 64 * WP / 8; t += 256){ lhi[t] = ghi[t]; llo[t] = glo[t]; }
    }
    __syncthreads();

    f32x4 acc[4];
    #pragma unroll
    for (int i = 0; i < 4; ++i) acc[i] = (f32x4){0.f, 0.f, 0.f, 0.f};

    #pragma unroll
    for (int ks = 0; ks < 2; ++ks) {
        const int k0 = ks * 32 + quad * 8;
        short8 ahi, alo;
        #pragma unroll
        for (int e = 0; e < 8; ++e) {
            float v = fdir[ks * 8 + e];
            short hi = bf16_rne(v);
            ahi[e] = hi;
            alo[e] = bf16_rne(v - bf16_to_f(hi));
        }
        #pragma unroll
        for (int nt = 0; nt < 4; ++nt) {
            short8 bhi = *(const short8*)(whi + (nt * 16 + ln) * WP + k0);
            short8 blo = *(const short8*)(wlo + (nt * 16 + ln) * WP + k0);
            acc[nt] = __builtin_amdgcn_mfma_f32_16x16x32_bf16(ahi, bhi, acc[nt], 0, 0, 0);
            acc[nt] = __builtin_amdgcn_mfma_f32_16x16x32_bf16(alo, bhi, acc[nt], 0, 0, 0);
            acc[nt] = __builtin_amdgcn_mfma_f32_16x16x32_bf16(ahi, blo, acc[nt], 0, 0, 0);
        }
    }

    float d1v[4], w2v[4];
    #pragma unroll
    for (int nt = 0; nt < 4; ++nt){
        d1v[nt] = d1p[nt * 16 + ln];
        w2v[nt] = Ws2[nt * 16 + ln];
    }
    float b2 = bs2[0];
    #pragma unroll
    for (int r = 0; r < 4; ++r){
        float t = 0.f;
        #pragma unroll
        for (int nt = 0; nt < 4; ++nt)
            t = fmaf(fmaxf(acc[nt][r] + d1v[nt], 0.f), w2v[nt], t);
        #pragma unroll
        for (int off = 1; off < 16; off <<= 1) t += __shfl_xor(t, off);
        if (ln == 0){
            int n = n0 + wv * 16 + quad * 4 + r;
            if (n < N) out[n] = t + b2;
        }
    }
}

// ---------------- launch ----------------

extern "C" void kernel_launch(void* const* d_in, const int* in_sizes, int n_in,
                              void* d_out, int out_size, void* d_ws, size_t ws_size,
                              hipStream_t stream)
{
    const float* x    = (const float*)d_in[0];
    const int*   ei   = (const int*)  d_in[1];
    const float* donor= (const float*)d_in[2];
    const float* W1   = (const float*)d_in[3];
    const float* as1  = (const float*)d_in[4];
    const float* ad1  = (const float*)d_in[5];
    const float* b1   = (const float*)d_in[6];
    const float* W2   = (const float*)d_in[7];
    const float* as2  = (const float*)d_in[8];
    const float* ad2  = (const float*)d_in[9];
    const float* b2   = (const float*)d_in[10];
    const float* Ws1  = (const float*)d_in[11];
    const float* bs1  = (const float*)d_in[12];
    const float* Ws2  = (const float*)d_in[13];
    const float* bs2  = (const float*)d_in[14];

    const int N  = in_sizes[0] / 27;
    const int E  = in_sizes[1] / 2;
    const int ET = E + N;
    const int NB = (N + 255) / 256;

    char* ws = (char*)d_ws;
    auto alloc = [&](size_t bytes) -> void* {
        void* p = (void*)ws;
        ws += (bytes + 255) / 256 * 256;
        return p;
    };
    int*      rowptr  = (int*)     alloc((size_t)(N + 1) * 4);
    int*      colsrc  = (int*)     alloc((size_t)ET * 4);
    unsigned* pairs   = (unsigned*)alloc((size_t)ET * 4);
    __half*   hbig    = (__half*)  alloc((size_t)N * HC * 2);
    float*    asrc    = (float*)   alloc((size_t)N * 4 * 4);
    float*    adst    = (float*)   alloc((size_t)N * 4 * 4);
    float*    hmid    = (float*)   alloc((size_t)N * CH * 4);
    uint2*    alpha   = (uint2*)   alloc((size_t)ET * 8);
    int*      bucket_cnt    = (int*) alloc(256 * 4);
    int*      bucket_cursor = (int*) alloc(256 * 4);   // contiguous with bucket_cnt
    short*    w1hi    = (short*)   alloc(256 * 40 * 2);
    short*    w2hi    = (short*)   alloc(256 * 72 * 2);
    short*    s1hi    = (short*)   alloc(64 * 72 * 2);
    short*    s1lo    = (short*)   alloc(64 * 72 * 2);
    float*    d1p     = (float*)   alloc(64 * 4);

    const int nblk = (N + 63) / 64;
    const int hblk = (ET + 2047) / 2048;
    const int sblk = 8 * ((N + 7) / 8);

    (void)hipMemsetAsync(bucket_cnt, 0, 512 * 4, stream);
    prep_hist_kernel<<<256 + hblk, 256, 0, stream>>>(W1, W2, Ws1, bs1, donor,
        w1hi, w2hi, s1hi, s1lo, d1p, ei, E, N, NB, bucket_cnt);
    coarse_scatter_kernel<<<hblk, 256, 0, stream>>>(ei, E, N, NB, bucket_cnt, bucket_cursor, pairs);
    transform1_fine_kernel<<<nblk + NB, 256, 0, stream>>>(
        x, w1hi, as1, ad1, hbig, asrc, adst, N,
        nblk, pairs, bucket_cnt, NB, colsrc, rowptr, ET);
    edge_alpha_kernel<<<(N + 7) / 8, 256, 0, stream>>>(
        rowptr, colsrc, asrc, adst, alpha, N);
    aggregate_slice_kernel<<<sblk, 256, 0, stream>>>(
        rowptr, colsrc, alpha, hbig, b1, hmid, N);
    transform2_kernel<<<nblk, 256, 0, stream>>>(
        hmid, w2hi, as2, ad2, hbig, asrc, adst, N);
    edge_alpha_kernel<<<(N + 7) / 8, 256, 0, stream>>>(
        rowptr, colsrc, asrc, adst, alpha, N);
    aggregate_slice_kernel<<<sblk, 256, 0, stream>>>(
        rowptr, colsrc, alpha, hbig, b2, hmid, N);
    scorer_mfma_kernel<<<nblk, 256, 0, stream>>>(
        hmid, s1hi, s1lo, d1p, Ws2, bs2, (float*)d_out, N);
}

// Round 7
// 298.802 us; speedup vs baseline: 1.5223x; 1.5223x over previous
//
#include <hip/hip_runtime.h>
#include <hip/hip_fp16.h>
#include <cmath>

#define HEADS 4
#define CH 64
#define HC 256
#define NEG 0.2f

typedef __attribute__((ext_vector_type(8))) short short8;
typedef __attribute__((ext_vector_type(4))) float f32x4;
typedef __fp16 half2_t __attribute__((ext_vector_type(2)));

__device__ __forceinline__ float leaky(float v){ return v > 0.f ? v : NEG * v; }

__device__ __forceinline__ short bf16_rne(float f){
    unsigned u = __float_as_uint(f);
    unsigned r = u + 0x7fffu + ((u >> 16) & 1u);
    return (short)(r >> 16);
}
__device__ __forceinline__ float bf16_to_f(short s){
    return __uint_as_float(((unsigned)(unsigned short)s) << 16);
}
__device__ __forceinline__ half2_t bc16(unsigned u){ return __builtin_bit_cast(half2_t, u); }
__device__ __forceinline__ unsigned packh2(float a, float b){
    __half ha = __float2half(a), hb = __float2half(b);   // RNE
    return (unsigned)__builtin_bit_cast(unsigned short, ha)
         | ((unsigned)__builtin_bit_cast(unsigned short, hb) << 16);
}
__device__ __forceinline__ float fd2(unsigned hv, unsigned w, float acc){
    return __builtin_amdgcn_fdot2(bc16(hv), bc16(w), acc, false);
}

// block-wide exclusive scan of one int per thread (256 threads)
__device__ __forceinline__ int block_excl_scan(int v, int* ws4){
    int tid = threadIdx.x, lane = tid & 63, wv = tid >> 6;
    int incl = v;
    #pragma unroll
    for (int off = 1; off < 64; off <<= 1){
        int t = __shfl_up(incl, off);
        if (lane >= off) incl += t;
    }
    if (lane == 63) ws4[wv] = incl;
    __syncthreads();
    int add = 0;
    for (int w = 0; w < wv; ++w) add += ws4[w];
    return incl - v + add;
}

// ---------------- prep (+ edge histogram tail) ----------------

__global__ __launch_bounds__(256) void prep_hist_kernel(
    const float* __restrict__ W1, const float* __restrict__ W2,
    const float* __restrict__ Ws1, const float* __restrict__ bs1,
    const float* __restrict__ donor,
    short* __restrict__ w1hi, short* __restrict__ w2hi,
    float* __restrict__ d1p,
    const int* __restrict__ ei, int E, int N, int NB, int* __restrict__ bucket_cnt)
{
    if ((int)blockIdx.x < 256){
        int t = blockIdx.x * 256 + threadIdx.x;
        int T = 256 * 256;
        for (int i = t; i < 256 * 40; i += T){                  // W1 bf16: [n=256][k pitch 40], K=27
            int n = i / 40, k = i % 40;
            w1hi[i] = bf16_rne((k < 27) ? W1[(size_t)k * HC + n] : 0.f);
        }
        for (int i = t; i < 256 * 72; i += T){                  // W2 bf16: [n=256][k pitch 72], K=64
            int n = i / 72, k = i % 72;
            w2hi[i] = bf16_rne((k < 64) ? W2[(size_t)k * HC + n] : 0.f);
        }
        if (t < 64){
            float s = bs1[t];
            for (int k = 0; k < 32; ++k) s = fmaf(donor[k], Ws1[(size_t)(64 + k) * 64 + t], s);
            d1p[t] = s;
        }
    } else {
        __shared__ int lh[256];
        int tid = threadIdx.x;
        int ET = E + N;
        int ebase = ((int)blockIdx.x - 256) * 2048;
        lh[tid] = 0;
        __syncthreads();
        #pragma unroll
        for (int j = 0; j < 8; ++j){
            int e = ebase + j * 256 + tid;
            if (e < ET){
                int d = (e < E) ? ei[E + e] : (e - E);
                atomicAdd(&lh[d >> 8], 1);
            }
        }
        __syncthreads();
        if (tid < NB && lh[tid]) atomicAdd(&bucket_cnt[tid], lh[tid]);
    }
}

// ---------------- coarse scatter (self-scan, packed uint32 pairs) ----------------

__global__ __launch_bounds__(256) void coarse_scatter_kernel(
    const int* __restrict__ ei, int E, int N, int NB,
    const int* __restrict__ bucket_cnt, int* __restrict__ bucket_cursor,
    unsigned* __restrict__ pairs)
{
    __shared__ int ws4[4];
    __shared__ int gbase[256];
    __shared__ int lh[256];
    __shared__ int gb[256];
    int tid = threadIdx.x;
    int ET = E + N;
    {
        int v = (tid < NB) ? bucket_cnt[tid] : 0;
        gbase[tid] = block_excl_scan(v, ws4);
    }
    lh[tid] = 0;
    __syncthreads();
    int ebase = blockIdx.x * 2048;
    int d[8], s[8], r[8];
    #pragma unroll
    for (int j = 0; j < 8; ++j){
        int e = ebase + j * 256 + tid;
        d[j] = -1;
        if (e < ET){
            if (e < E){ s[j] = ei[e]; d[j] = ei[E + e]; } else { s[j] = d[j] = e - E; }
            r[j] = atomicAdd(&lh[d[j] >> 8], 1);
        }
    }
    __syncthreads();
    if (tid < NB && lh[tid]) gb[tid] = gbase[tid] + atomicAdd(&bucket_cursor[tid], lh[tid]);
    __syncthreads();
    #pragma unroll
    for (int j = 0; j < 8; ++j){
        if (d[j] >= 0)
            pairs[gb[d[j] >> 8] + r[j]] = ((unsigned)d[j] << 16) | (unsigned)s[j];
    }
}

// ---------------- fine sort body (self-scan, block-local writes) ----------------

__device__ __forceinline__ void fine_sort_body(
    int b, const unsigned* __restrict__ pairs, const int* __restrict__ bucket_cnt, int NB,
    int* __restrict__ colsrc, int* __restrict__ rowptr, int N, int ET)
{
    __shared__ int ws4f[4];
    __shared__ int sb[257];
    __shared__ int hist[256];
    __shared__ int cur[256];
    int tid = threadIdx.x;
    {
        int v = (tid < NB) ? bucket_cnt[tid] : 0;
        int excl = block_excl_scan(v, ws4f);
        sb[tid] = excl;
        if (tid == 255) sb[256] = excl + v;
    }
    hist[tid] = 0;
    __syncthreads();
    int base = sb[b], endb = sb[b + 1];
    int cnt = endb - base;
    int d0 = b << 8;
    for (int i = tid; i < cnt; i += 256){
        unsigned p = pairs[base + i];
        atomicAdd(&hist[(int)(p >> 16) - d0], 1);
    }
    __syncthreads();
    int v = hist[tid];
    int excl = block_excl_scan(v, ws4f);
    cur[tid] = excl;
    if (d0 + tid < N) rowptr[d0 + tid] = base + excl;
    if (b == 0 && tid == 0) rowptr[N] = ET;
    __syncthreads();
    for (int i = tid; i < cnt; i += 256){
        unsigned p = pairs[base + i];
        int r = atomicAdd(&cur[(int)(p >> 16) - d0], 1);
        colsrc[base + r] = (int)(p & 0xFFFFu);
    }
}

// ---------------- MFMA node transform (device body) ----------------
// X3: bf16x3 A*B split. DIRECT: FIN==64, read A-fragments straight from global
// (contiguous 32B/lane, wave covers 16 consecutive rows) — no xl staging.

template<int FIN, int KSTEPS, int NT, bool X3, bool DIRECT>
__device__ __forceinline__ void transform_body(
    int bx, int by,
    const float* __restrict__ xin, const short* __restrict__ whi, const short* __restrict__ wlo,
    const float* __restrict__ a_src, const float* __restrict__ a_dst,
    __half* __restrict__ h, float* __restrict__ asrc, float* __restrict__ adst, int N)
{
    constexpr int KP = KSTEPS * 32;
    constexpr int XP = KP + 4;
    constexpr int WP = KP + 8;
    constexpr int NCOL = NT * 16;
    __shared__ float xl[DIRECT ? 8 : 64 * XP];
    __shared__ short wt_hi[NCOL * WP];
    __shared__ short wt_lo[X3 ? NCOL * WP : 8];

    const int tid = threadIdx.x;
    const int n0 = bx * 64;
    const int c0 = by * NCOL;

    const int wv = tid >> 6, lane = tid & 63;
    const int quad = lane >> 4, ln = lane & 15;
    const int myrow = wv * 16 + ln;

    float fdir[DIRECT ? KSTEPS * 8 : 1];
    if (DIRECT){
        int n = n0 + myrow;
        #pragma unroll
        for (int ks = 0; ks < KSTEPS; ++ks){
            float4 f0 = make_float4(0.f, 0.f, 0.f, 0.f), f1 = f0;
            if (n < N){
                const float* ap = xin + (size_t)n * FIN + ks * 32 + quad * 8;
                f0 = *(const float4*)ap;
                f1 = *(const float4*)(ap + 4);
            }
            fdir[ks*8+0]=f0.x; fdir[ks*8+1]=f0.y; fdir[ks*8+2]=f0.z; fdir[ks*8+3]=f0.w;
            fdir[ks*8+4]=f1.x; fdir[ks*8+5]=f1.y; fdir[ks*8+6]=f1.z; fdir[ks*8+7]=f1.w;
        }
    } else {
        for (int t = tid; t < 64 * KP; t += 256) {
            int row = t / KP, k = t % KP;
            int n = n0 + row;
            float v = 0.f;
            if (n < N && k < FIN) v = xin[(size_t)n * FIN + k];
            xl[row * XP + k] = v;
        }
    }
    {
        const short8* ghi = (const short8*)(whi + (size_t)c0 * WP);
        short8* lhi = (short8*)wt_hi;
        for (int t = tid; t < NCOL * WP / 8; t += 256) lhi[t] = ghi[t];
        if (X3){
            const short8* glo = (const short8*)(wlo + (size_t)c0 * WP);
            short8* llo = (short8*)wt_lo;
            for (int t = tid; t < NCOL * WP / 8; t += 256) llo[t] = glo[t];
        }
    }
    __syncthreads();

    f32x4 acc[NT];
    #pragma unroll
    for (int i = 0; i < NT; ++i) acc[i] = (f32x4){0.f, 0.f, 0.f, 0.f};

    #pragma unroll
    for (int ks = 0; ks < KSTEPS; ++ks) {
        const int k0 = ks * 32 + quad * 8;
        float fa[8];
        if (DIRECT){
            #pragma unroll
            for (int e = 0; e < 8; ++e) fa[e] = fdir[ks * 8 + e];
        } else {
            const float* ap = xl + myrow * XP + k0;
            float4 f0 = *(const float4*)ap;
            float4 f1 = *(const float4*)(ap + 4);
            fa[0]=f0.x; fa[1]=f0.y; fa[2]=f0.z; fa[3]=f0.w;
            fa[4]=f1.x; fa[5]=f1.y; fa[6]=f1.z; fa[7]=f1.w;
        }
        short8 ahi, alo;
        #pragma unroll
        for (int e = 0; e < 8; ++e) {
            short hi = bf16_rne(fa[e]);
            ahi[e] = hi;
            alo[e] = bf16_rne(fa[e] - bf16_to_f(hi));
        }
        #pragma unroll
        for (int nt = 0; nt < NT; ++nt) {
            short8 bhi = *(const short8*)(wt_hi + (nt * 16 + ln) * WP + k0);
            acc[nt] = __builtin_amdgcn_mfma_f32_16x16x32_bf16(ahi, bhi, acc[nt], 0, 0, 0);
            acc[nt] = __builtin_amdgcn_mfma_f32_16x16x32_bf16(alo, bhi, acc[nt], 0, 0, 0);
            if (X3){
                short8 blo = *(const short8*)(wt_lo + (nt * 16 + ln) * WP + k0);
                acc[nt] = __builtin_amdgcn_mfma_f32_16x16x32_bf16(ahi, blo, acc[nt], 0, 0, 0);
            }
        }
    }

    #pragma unroll
    for (int r = 0; r < 4; ++r) {
        int n = n0 + wv * 16 + quad * 4 + r;
        if (n < N) {
            if (NT == 16) {
                #pragma unroll
                for (int q = 0; q < 4; ++q) {
                    uint2 u;
                    u.x = packh2(acc[q][r],     acc[q + 4][r]);
                    u.y = packh2(acc[q + 8][r], acc[q + 12][r]);
                    *(uint2*)((char*)h + (size_t)n * 512 + (q * 16 + ln) * 8) = u;
                }
            } else {
                #pragma unroll
                for (int q = 0; q < 4; ++q) {
                    unsigned u = packh2(acc[q][r], acc[q + 4][r]);
                    *(unsigned*)((char*)h + (size_t)n * 512 + (q * 16 + ln) * 8 + ((c0 >> 6) << 1)) = u;
                }
            }
        }
    }

    float aS[NT], aD[NT];
    #pragma unroll
    for (int nt = 0; nt < NT; ++nt) {
        aS[nt] = a_src[c0 + nt * 16 + ln];
        aD[nt] = a_dst[c0 + nt * 16 + ln];
    }
    #pragma unroll
    for (int hl = 0; hl < NT / 4; ++hl) {
        #pragma unroll
        for (int r = 0; r < 4; ++r) {
            float ps = 0.f, pd = 0.f;
            #pragma unroll
            for (int i = 0; i < 4; ++i) {
                ps = fmaf(acc[hl * 4 + i][r], aS[hl * 4 + i], ps);
                pd = fmaf(acc[hl * 4 + i][r], aD[hl * 4 + i], pd);
            }
            #pragma unroll
            for (int off = 1; off < 16; off <<= 1) {
                ps += __shfl_xor(ps, off);
                pd += __shfl_xor(pd, off);
            }
            if (ln == 0) {
                int n = n0 + wv * 16 + quad * 4 + r;
                if (n < N) {
                    int hg = c0 / 64 + hl;
                    asrc[n * 4 + hg] = ps;
                    adst[n * 4 + hg] = pd;
                }
            }
        }
    }
}

// transform1 (bf16x2, LDS-staged x: FIN=27) fused with fine-sort tail blocks
__global__ __launch_bounds__(256) void transform1_fine_kernel(
    const float* __restrict__ xin, const short* __restrict__ whi,
    const float* __restrict__ a_src, const float* __restrict__ a_dst,
    __half* __restrict__ h, float* __restrict__ asrc, float* __restrict__ adst, int N,
    int nblk, const unsigned* __restrict__ pairs, const int* __restrict__ bucket_cnt, int NB,
    int* __restrict__ colsrc, int* __restrict__ rowptr, int ET)
{
    if ((int)blockIdx.x < nblk) {
        transform_body<27, 1, 16, false, false>(blockIdx.x, 0, xin, whi, nullptr,
                                                a_src, a_dst, h, asrc, adst, N);
    } else {
        fine_sort_body(blockIdx.x - nblk, pairs, bucket_cnt, NB, colsrc, rowptr, N, ET);
    }
}

// transform2: NT=16 single pass, bf16x2, DIRECT global A reads (36.9 KB LDS)
__global__ __launch_bounds__(256) void transform2_kernel(
    const float* __restrict__ xin, const short* __restrict__ whi,
    const float* __restrict__ a_src, const float* __restrict__ a_dst,
    __half* __restrict__ h, float* __restrict__ asrc, float* __restrict__ adst, int N)
{
    transform_body<64, 2, 16, false, true>(blockIdx.x, 0, xin, whi, nullptr,
                                           a_src, a_dst, h, asrc, adst, N);
}

// ---------------- per-dst aggregation: 2 nodes/wave, shfl-broadcast sweep ----------------
// r0 structure (proven 64us floor for the ~200MB random-512B gather; r1-r6
// showed depth/width/residency restructures all lose). SCORE=1 additionally
// fuses the scorer MLP: each 32-lane group holds node n's post-ELU hmid row
// in registers (2ch/lane) -> relu(hmid@Ws1[0:64]+d1p)@Ws2+bs2 computed via
// LDS-staged Ws1 (16KB f32) + shfl broadcast. Deletes the scorer kernel, its
// 12.8MB hmid re-read, and aggregate2's 12.5MB hmid write. f32 fmaf path is
// MORE accurate than the bf16x3 MFMA scorer it replaces.

template<int SCORE>
__global__ __launch_bounds__(256) void aggregate_kernel(
    const int* __restrict__ rowptr, const int* __restrict__ colsrc,
    const __half* __restrict__ h, const float* __restrict__ asrc,
    const float* __restrict__ adst, const float* __restrict__ bias,
    float* __restrict__ hout, int N,
    const float* __restrict__ Ws1g, const float* __restrict__ d1pg,
    const float* __restrict__ Ws2g, const float* __restrict__ bs2g,
    float* __restrict__ outg)
{
    __shared__ float ws1L[SCORE ? 4096 : 8];
    int tid = threadIdx.x;
    int grp = tid >> 5;
    int lane32 = tid & 31;
    int n = blockIdx.x * 8 + grp;

    if (SCORE){
        const float4* g = (const float4*)Ws1g;           // first 64 rows of [96][64]
        float4* l = (float4*)ws1L;
        for (int t = tid; t < 1024; t += 256) l[t] = g[t];
        __syncthreads();
    }
    if (n >= N) return;

    int start = rowptr[n], end = rowptr[n + 1];
    int deg = end - start;
    const float4 ad = *(const float4*)(adst + (size_t)n * 4);

    int src0 = 0;
    float e0 = -1e30f, e1 = -1e30f, e2 = -1e30f, e3 = -1e30f;
    bool v0 = lane32 < deg;
    if (v0){
        src0 = colsrc[start + lane32];
        float4 as = *(const float4*)(asrc + (size_t)src0 * 4);
        e0 = leaky(as.x + ad.x); e1 = leaky(as.y + ad.y);
        e2 = leaky(as.z + ad.z); e3 = leaky(as.w + ad.w);
    }

    float m0, m1, m2, m3, i0, i1, i2, i3, p0, p1, p2, p3;
    if (deg <= 32){
        m0 = e0; m1 = e1; m2 = e2; m3 = e3;
        #pragma unroll
        for (int off = 1; off < 32; off <<= 1){
            m0 = fmaxf(m0, __shfl_xor(m0, off));
            m1 = fmaxf(m1, __shfl_xor(m1, off));
            m2 = fmaxf(m2, __shfl_xor(m2, off));
            m3 = fmaxf(m3, __shfl_xor(m3, off));
        }
        p0 = __expf(e0 - m0);
        p1 = __expf(e1 - m1);
        p2 = __expf(e2 - m2);
        p3 = __expf(e3 - m3);
        float t0 = p0, t1 = p1, t2 = p2, t3 = p3;
        #pragma unroll
        for (int off = 1; off < 32; off <<= 1){
            t0 += __shfl_xor(t0, off);
            t1 += __shfl_xor(t1, off);
            t2 += __shfl_xor(t2, off);
            t3 += __shfl_xor(t3, off);
        }
        i0 = 1.f / t0; i1 = 1.f / t1; i2 = 1.f / t2; i3 = 1.f / t3;
    } else {
        m0 = e0; m1 = e1; m2 = e2; m3 = e3;
        float t0 = v0 ? 1.f : 0.f, t1 = t0, t2 = t0, t3 = t0;
        for (int i = start + 32 + lane32; i < end; i += 32){
            int s = colsrc[i];
            float4 as = *(const float4*)(asrc + (size_t)s * 4);
            float e, nm;
            e = leaky(as.x + ad.x); nm = fmaxf(m0, e); t0 = t0 * __expf(m0 - nm) + __expf(e - nm); m0 = nm;
            e = leaky(as.y + ad.y); nm = fmaxf(m1, e); t1 = t1 * __expf(m1 - nm) + __expf(e - nm); m1 = nm;
            e = leaky(as.z + ad.z); nm = fmaxf(m2, e); t2 = t2 * __expf(m2 - nm) + __expf(e - nm); m2 = nm;
            e = leaky(as.w + ad.w); nm = fmaxf(m3, e); t3 = t3 * __expf(m3 - nm) + __expf(e - nm); m3 = nm;
        }
        #pragma unroll
        for (int off = 1; off < 32; off <<= 1){
            float om, os, nm;
            om = __shfl_xor(m0, off); os = __shfl_xor(t0, off);
            nm = fmaxf(m0, om); t0 = t0 * __expf(m0 - nm) + os * __expf(om - nm); m0 = nm;
            om = __shfl_xor(m1, off); os = __shfl_xor(t1, off);
            nm = fmaxf(m1, om); t1 = t1 * __expf(m1 - nm) + os * __expf(om - nm); m1 = nm;
            om = __shfl_xor(m2, off); os = __shfl_xor(t2, off);
            nm = fmaxf(m2, om); t2 = t2 * __expf(m2 - nm) + os * __expf(om - nm); m2 = nm;
            om = __shfl_xor(m3, off); os = __shfl_xor(t3, off);
            nm = fmaxf(m3, om); t3 = t3 * __expf(m3 - nm) + os * __expf(om - nm); m3 = nm;
        }
        i0 = 1.f / t0; i1 = 1.f / t1; i2 = 1.f / t2; i3 = 1.f / t3;
        p0 = __expf(e0 - m0); p1 = __expf(e1 - m1);
        p2 = __expf(e2 - m2); p3 = __expf(e3 - m3);
    }

    float accA = 0.f, accB = 0.f;
    const int boff = lane32 * 16;
    bool first = true;
    for (int base = start; base < end; base += 32){
        int cnt = end - base; if (cnt > 32) cnt = 32;
        float w0, w1, w2, w3; int off = 0;
        if (first){
            w0 = p0 * i0; w1 = p1 * i1; w2 = p2 * i2; w3 = p3 * i3;
            off = v0 ? src0 * (HC * 2) : 0;
        } else {
            w0 = w1 = w2 = w3 = 0.f;
            if (lane32 < cnt){
                int s = colsrc[base + lane32];
                float4 as = *(const float4*)(asrc + (size_t)s * 4);
                w0 = __expf(leaky(as.x + ad.x) - m0) * i0;
                w1 = __expf(leaky(as.y + ad.y) - m1) * i1;
                w2 = __expf(leaky(as.z + ad.z) - m2) * i2;
                w3 = __expf(leaky(as.w + ad.w) - m3) * i3;
                off = s * (HC * 2);
            }
        }
        first = false;
        half2_t q01 = __builtin_amdgcn_cvt_pkrtz(w0, w1);
        half2_t q23 = __builtin_amdgcn_cvt_pkrtz(w2, w3);
        unsigned wx = __builtin_bit_cast(unsigned, q01);
        unsigned wy = __builtin_bit_cast(unsigned, q23);

        int j = 0;
        for (; j + 2 <= cnt; j += 2){
            int o0 = __shfl(off, j, 32);
            unsigned a0 = __shfl((int)wx, j, 32), b0 = __shfl((int)wy, j, 32);
            int o1 = __shfl(off, j + 1, 32);
            unsigned a1 = __shfl((int)wx, j + 1, 32), b1 = __shfl((int)wy, j + 1, 32);
            uint4 h0 = *(const uint4*)((const char*)h + o0 + boff);
            uint4 h1 = *(const uint4*)((const char*)h + o1 + boff);
            accA = fd2(h0.x, a0, accA); accA = fd2(h0.y, b0, accA);
            accB = fd2(h0.z, a0, accB); accB = fd2(h0.w, b0, accB);
            accA = fd2(h1.x, a1, accA); accA = fd2(h1.y, b1, accA);
            accB = fd2(h1.z, a1, accB); accB = fd2(h1.w, b1, accB);
        }
        for (; j < cnt; ++j){
            int o0 = __shfl(off, j, 32);
            unsigned a0 = __shfl((int)wx, j, 32), b0 = __shfl((int)wy, j, 32);
            uint4 h0 = *(const uint4*)((const char*)h + o0 + boff);
            accA = fd2(h0.x, a0, accA); accA = fd2(h0.y, b0, accA);
            accB = fd2(h0.z, a0, accB); accB = fd2(h0.w, b0, accB);
        }
    }

    float2 bv = *(const float2*)(bias + lane32 * 2);
    float oA = accA * 0.25f + bv.x;
    float oB = accB * 0.25f + bv.y;
    oA = (oA > 0.f) ? oA : expm1f(oA);
    oB = (oB > 0.f) ? oB : expm1f(oB);

    if (SCORE){
        // hidden[j] = relu(sum_c hm[c]*Ws1[c][j] + d1p[j]); logits = hidden@Ws2 + bs2
        float ha = d1pg[lane32], hb = d1pg[lane32 + 32];
        #pragma unroll
        for (int l = 0; l < 32; ++l){
            float va = __shfl(oA, l, 32);
            float vb = __shfl(oB, l, 32);
            ha = fmaf(va, ws1L[(2 * l) * 64 + lane32], ha);
            ha = fmaf(vb, ws1L[(2 * l + 1) * 64 + lane32], ha);
            hb = fmaf(va, ws1L[(2 * l) * 64 + lane32 + 32], hb);
            hb = fmaf(vb, ws1L[(2 * l + 1) * 64 + lane32 + 32], hb);
        }
        ha = fmaxf(ha, 0.f); hb = fmaxf(hb, 0.f);
        float t = fmaf(ha, Ws2g[lane32], hb * Ws2g[lane32 + 32]);
        #pragma unroll
        for (int off = 1; off < 32; off <<= 1) t += __shfl_xor(t, off);
        if (lane32 == 0) outg[n] = t + bs2g[0];
    } else {
        *(float2*)(hout + (size_t)n * CH + lane32 * 2) = make_float2(oA, oB);
    }
}

// ---------------- launch ----------------

extern "C" void kernel_launch(void* const* d_in, const int* in_sizes, int n_in,
                              void* d_out, int out_size, void* d_ws, size_t ws_size,
                              hipStream_t stream)
{
    const float* x    = (const float*)d_in[0];
    const int*   ei   = (const int*)  d_in[1];
    const float* donor= (const float*)d_in[2];
    const float* W1   = (const float*)d_in[3];
    const float* as1  = (const float*)d_in[4];
    const float* ad1  = (const float*)d_in[5];
    const float* b1   = (const float*)d_in[6];
    const float* W2   = (const float*)d_in[7];
    const float* as2  = (const float*)d_in[8];
    const float* ad2  = (const float*)d_in[9];
    const float* b2   = (const float*)d_in[10];
    const float* Ws1  = (const float*)d_in[11];
    const float* bs1  = (const float*)d_in[12];
    const float* Ws2  = (const float*)d_in[13];
    const float* bs2  = (const float*)d_in[14];

    const int N  = in_sizes[0] / 27;
    const int E  = in_sizes[1] / 2;
    const int ET = E + N;
    const int NB = (N + 255) / 256;

    char* ws = (char*)d_ws;
    auto alloc = [&](size_t bytes) -> void* {
        void* p = (void*)ws;
        ws += (bytes + 255) / 256 * 256;
        return p;
    };
    int*      rowptr  = (int*)     alloc((size_t)(N + 1) * 4);
    int*      colsrc  = (int*)     alloc((size_t)ET * 4);
    unsigned* pairs   = (unsigned*)alloc((size_t)ET * 4);
    __half*   hbig    = (__half*)  alloc((size_t)N * HC * 2);
    float*    asrc    = (float*)   alloc((size_t)N * 4 * 4);
    float*    adst    = (float*)   alloc((size_t)N * 4 * 4);
    float*    hmid    = (float*)   alloc((size_t)N * CH * 4);
    int*      bucket_cnt    = (int*) alloc(256 * 4);
    int*      bucket_cursor = (int*) alloc(256 * 4);   // contiguous with bucket_cnt
    short*    w1hi    = (short*)   alloc(256 * 40 * 2);
    short*    w2hi    = (short*)   alloc(256 * 72 * 2);
    float*    d1p     = (float*)   alloc(64 * 4);

    const int nblk = (N + 63) / 64;
    const int hblk = (ET + 2047) / 2048;

    (void)hipMemsetAsync(bucket_cnt, 0, 512 * 4, stream);
    prep_hist_kernel<<<256 + hblk, 256, 0, stream>>>(W1, W2, Ws1, bs1, donor,
        w1hi, w2hi, d1p, ei, E, N, NB, bucket_cnt);
    coarse_scatter_kernel<<<hblk, 256, 0, stream>>>(ei, E, N, NB, bucket_cnt, bucket_cursor, pairs);
    transform1_fine_kernel<<<nblk + NB, 256, 0, stream>>>(
        x, w1hi, as1, ad1, hbig, asrc, adst, N,
        nblk, pairs, bucket_cnt, NB, colsrc, rowptr, ET);
    aggregate_kernel<0><<<(N + 7) / 8, 256, 0, stream>>>(
        rowptr, colsrc, hbig, asrc, adst, b1, hmid, N,
        nullptr, nullptr, nullptr, nullptr, nullptr);
    transform2_kernel<<<nblk, 256, 0, stream>>>(
        hmid, w2hi, as2, ad2, hbig, asrc, adst, N);
    aggregate_kernel<1><<<(N + 7) / 8, 256, 0, stream>>>(
        rowptr, colsrc, hbig, asrc, adst, b2, nullptr, N,
        Ws1, d1p, Ws2, bs2, (float*)d_out);
}

// Round 9
// 233.341 us; speedup vs baseline: 1.9493x; 1.2805x over previous
//
#include <hip/hip_runtime.h>
#include <hip/hip_fp16.h>
#include <cmath>

#define NEG 0.2f

typedef __attribute__((ext_vector_type(8))) short short8;
typedef __attribute__((ext_vector_type(4))) float f32x4;
typedef __fp16 half2_t __attribute__((ext_vector_type(2)));

__device__ __forceinline__ float leaky(float v){ return v > 0.f ? v : NEG * v; }

__device__ __forceinline__ short bf16_rne(float f){
    unsigned u = __float_as_uint(f);
    unsigned r = u + 0x7fffu + ((u >> 16) & 1u);
    return (short)(r >> 16);
}
__device__ __forceinline__ float bf16_to_f(short s){
    return __uint_as_float(((unsigned)(unsigned short)s) << 16);
}
__device__ __forceinline__ half2_t bc16(unsigned u){ return __builtin_bit_cast(half2_t, u); }
__device__ __forceinline__ unsigned packh2(float a, float b){
    __half ha = __float2half(a), hb = __float2half(b);   // RNE
    return (unsigned)__builtin_bit_cast(unsigned short, ha)
         | ((unsigned)__builtin_bit_cast(unsigned short, hb) << 16);
}

// block-wide exclusive scan of one int per thread (256 threads)
__device__ __forceinline__ int block_excl_scan(int v, int* ws4){
    int tid = threadIdx.x, lane = tid & 63, wv = tid >> 6;
    int incl = v;
    #pragma unroll
    for (int off = 1; off < 64; off <<= 1){
        int t = __shfl_up(incl, off);
        if (lane >= off) incl += t;
    }
    if (lane == 63) ws4[wv] = incl;
    __syncthreads();
    int add = 0;
    for (int w = 0; w < wv; ++w) add += ws4[w];
    return incl - v + add;
}

// ---------------- prep (+ edge histogram tail) ----------------
// AGGREGATE-FIRST restructure (r8): GAT linearity  sum_e a[e,h]*(W x)[src]
// = W_h * (sum_e a[e,h] x[src]),  alpha_src[n,h] = x[n] . (W_h^T a_src[h]).
// So gathers move to RAW features (128B rows, not 512B h rows) and the
// per-head GEMMs run on dense G tensors after aggregation. Prep builds:
//  w1p bf16 [c=64][kk=136]: kk=h*32+k (k<27), val = W1[k,h*64+c]/4
//  w2p bf16 [c=64][kk=264]: kk=h*64+k,        val = W2[k,h*64+c]/4
//  hat1s/d [4][32] = W1_h^T a1,  hat2s/d [4][64] = W2_h^T a2
//  s1hi/s1lo, d1p: scorer (unchanged)

__global__ __launch_bounds__(256) void prep_hist_kernel(
    const float* __restrict__ W1, const float* __restrict__ W2,
    const float* __restrict__ Ws1, const float* __restrict__ bs1,
    const float* __restrict__ donor,
    const float* __restrict__ as1, const float* __restrict__ ad1,
    const float* __restrict__ as2, const float* __restrict__ ad2,
    short* __restrict__ w1p, short* __restrict__ w2p,
    short* __restrict__ s1hi, short* __restrict__ s1lo, float* __restrict__ d1p,
    float* __restrict__ hat1s, float* __restrict__ hat1d,
    float* __restrict__ hat2s, float* __restrict__ hat2d,
    const int* __restrict__ ei, int E, int N, int NB, int* __restrict__ bucket_cnt)
{
    if ((int)blockIdx.x < 256){
        int t = blockIdx.x * 256 + threadIdx.x;
        int T = 256 * 256;
        for (int i = t; i < 64 * 136; i += T){
            int c = i / 136, kk = i % 136; short v = 0;
            if (kk < 128){ int h = kk >> 5, k = kk & 31;
                if (k < 27) v = bf16_rne(W1[(size_t)k * 256 + h * 64 + c] * 0.25f); }
            w1p[i] = v;
        }
        for (int i = t; i < 64 * 264; i += T){
            int c = i / 264, kk = i % 264; short v = 0;
            if (kk < 256){ int h = kk >> 6, k = kk & 63;
                v = bf16_rne(W2[(size_t)k * 256 + h * 64 + c] * 0.25f); }
            w2p[i] = v;
        }
        for (int i = t; i < 64 * 72; i += T){
            int nn = i / 72, k = i % 72;
            float v = (k < 64) ? Ws1[(size_t)k * 64 + nn] : 0.f;
            short hi = bf16_rne(v);
            s1hi[i] = hi; s1lo[i] = bf16_rne(v - bf16_to_f(hi));
        }
        if (t < 64){
            float s = bs1[t];
            for (int k = 0; k < 32; ++k) s = fmaf(donor[k], Ws1[(size_t)(64 + k) * 64 + t], s);
            d1p[t] = s;
        }
        if (t < 128){
            int h = t >> 5, k = t & 31;
            float s = 0.f, d = 0.f;
            if (k < 27)
                for (int c = 0; c < 64; ++c){
                    float w = W1[(size_t)k * 256 + h * 64 + c];
                    s = fmaf(w, as1[h * 64 + c], s);
                    d = fmaf(w, ad1[h * 64 + c], d);
                }
            hat1s[t] = s; hat1d[t] = d;
        }
        if (t < 256){
            int h = t >> 6, k = t & 63;
            float s = 0.f, d = 0.f;
            for (int c = 0; c < 64; ++c){
                float w = W2[(size_t)k * 256 + h * 64 + c];
                s = fmaf(w, as2[h * 64 + c], s);
                d = fmaf(w, ad2[h * 64 + c], d);
            }
            hat2s[t] = s; hat2d[t] = d;
        }
    } else {
        __shared__ int lh[256];
        int tid = threadIdx.x;
        int ET = E + N;
        int ebase = ((int)blockIdx.x - 256) * 2048;
        lh[tid] = 0;
        __syncthreads();
        #pragma unroll
        for (int j = 0; j < 8; ++j){
            int e = ebase + j * 256 + tid;
            if (e < ET){
                int d = (e < E) ? ei[E + e] : (e - E);
                atomicAdd(&lh[d >> 8], 1);
            }
        }
        __syncthreads();
        if (tid < NB && lh[tid]) atomicAdd(&bucket_cnt[tid], lh[tid]);
    }
}

// ---------------- coarse scatter (self-scan, packed uint32 pairs) ----------------

__global__ __launch_bounds__(256) void coarse_scatter_kernel(
    const int* __restrict__ ei, int E, int N, int NB,
    const int* __restrict__ bucket_cnt, int* __restrict__ bucket_cursor,
    unsigned* __restrict__ pairs)
{
    __shared__ int ws4[4];
    __shared__ int gbase[256];
    __shared__ int lh[256];
    __shared__ int gb[256];
    int tid = threadIdx.x;
    int ET = E + N;
    {
        int v = (tid < NB) ? bucket_cnt[tid] : 0;
        gbase[tid] = block_excl_scan(v, ws4);
    }
    lh[tid] = 0;
    __syncthreads();
    int ebase = blockIdx.x * 2048;
    int d[8], s[8], r[8];
    #pragma unroll
    for (int j = 0; j < 8; ++j){
        int e = ebase + j * 256 + tid;
        d[j] = -1;
        if (e < ET){
            if (e < E){ s[j] = ei[e]; d[j] = ei[E + e]; } else { s[j] = d[j] = e - E; }
            r[j] = atomicAdd(&lh[d[j] >> 8], 1);
        }
    }
    __syncthreads();
    if (tid < NB && lh[tid]) gb[tid] = gbase[tid] + atomicAdd(&bucket_cursor[tid], lh[tid]);
    __syncthreads();
    #pragma unroll
    for (int j = 0; j < 8; ++j){
        if (d[j] >= 0)
            pairs[gb[d[j] >> 8] + r[j]] = ((unsigned)d[j] << 16) | (unsigned)s[j];
    }
}

// ---------------- fine sort body (self-scan, block-local writes) ----------------

__device__ __forceinline__ void fine_sort_body(
    int b, const unsigned* __restrict__ pairs, const int* __restrict__ bucket_cnt, int NB,
    int* __restrict__ colsrc, int* __restrict__ rowptr, int N, int ET)
{
    __shared__ int ws4f[4];
    __shared__ int sb[257];
    __shared__ int hist[256];
    __shared__ int cur[256];
    int tid = threadIdx.x;
    {
        int v = (tid < NB) ? bucket_cnt[tid] : 0;
        int excl = block_excl_scan(v, ws4f);
        sb[tid] = excl;
        if (tid == 255) sb[256] = excl + v;
    }
    hist[tid] = 0;
    __syncthreads();
    int base = sb[b], endb = sb[b + 1];
    int cnt = endb - base;
    int d0 = b << 8;
    for (int i = tid; i < cnt; i += 256){
        unsigned p = pairs[base + i];
        atomicAdd(&hist[(int)(p >> 16) - d0], 1);
    }
    __syncthreads();
    int v = hist[tid];
    int excl = block_excl_scan(v, ws4f);
    cur[tid] = excl;
    if (d0 + tid < N) rowptr[d0 + tid] = base + excl;
    if (b == 0 && tid == 0) rowptr[N] = ET;
    __syncthreads();
    for (int i = tid; i < cnt; i += 256){
        unsigned p = pairs[base + i];
        int r = atomicAdd(&cur[(int)(p >> 16) - d0], 1);
        colsrc[base + r] = (int)(p & 0xFFFFu);
    }
}

// ---------------- x pack + layer-1 alphas, fused with fine-sort ----------------
// xp[N][32] f32 (27 real + 5 zero pad = 128B aligned row for the gather);
// asrc1/adst1[n,h] = x[n] . hat1[h] (exact f32).

__global__ __launch_bounds__(256) void xprep_fine_kernel(
    const float* __restrict__ x, const float* __restrict__ hat1s, const float* __restrict__ hat1d,
    float* __restrict__ xp, float* __restrict__ asrc, float* __restrict__ adst, int N,
    int XB, const unsigned* __restrict__ pairs, const int* __restrict__ bucket_cnt, int NB,
    int* __restrict__ colsrc, int* __restrict__ rowptr, int ET)
{
    if ((int)blockIdx.x < XB){
        int t0 = blockIdx.x * 256 + threadIdx.x, T = XB * 256;
        for (int i = t0; i < N * 32; i += T){
            int nn = i >> 5, k = i & 31;
            xp[i] = (k < 27) ? x[(size_t)nn * 27 + k] : 0.f;
        }
        for (int nn = t0; nn < N; nn += T){
            float xr[27];
            #pragma unroll
            for (int k = 0; k < 27; ++k) xr[k] = x[(size_t)nn * 27 + k];
            #pragma unroll
            for (int h = 0; h < 4; ++h){
                float s = 0.f, d = 0.f;
                #pragma unroll
                for (int k = 0; k < 27; ++k){
                    s = fmaf(xr[k], hat1s[h * 32 + k], s);
                    d = fmaf(xr[k], hat1d[h * 32 + k], d);
                }
                asrc[nn * 4 + h] = s;
                adst[nn * 4 + h] = d;
            }
        }
    } else {
        fine_sort_body(blockIdx.x - XB, pairs, bucket_cnt, NB, colsrc, rowptr, N, ET);
    }
}

// ---------------- aggregation (r0 softmax structure, 128B payload rows) ----------------
// L=1: payload xp f32[N][32], lane k accumulates acc[h] += a[e,h]*x[src,k];
//      G1 f32 [N][128] (kk=h*32+k).
// L=2: payload hmid fp16[N][64], lane owns 2 channels; G2 fp16 [N][256] (kk=h*64+k).
// Softmax/alpha math byte-identical to the proven r0 aggregate.

template<int L>
__device__ __forceinline__ void agg_edge(const char* __restrict__ pay, int boff, int o,
    unsigned aw, unsigned bw, float* accx, float* accy)
{
    half2_t ah = bc16(aw), bh = bc16(bw);
    float w0 = (float)ah[0], w1 = (float)ah[1], w2 = (float)bh[0], w3 = (float)bh[1];
    if (L == 1){
        float xv = *(const float*)(pay + o + boff);
        accx[0] = fmaf(w0, xv, accx[0]);
        accx[1] = fmaf(w1, xv, accx[1]);
        accx[2] = fmaf(w2, xv, accx[2]);
        accx[3] = fmaf(w3, xv, accx[3]);
    } else {
        unsigned hv = *(const unsigned*)(pay + o + boff);
        half2_t hh = bc16(hv);
        float c0 = (float)hh[0], c1 = (float)hh[1];
        accx[0] = fmaf(w0, c0, accx[0]); accy[0] = fmaf(w0, c1, accy[0]);
        accx[1] = fmaf(w1, c0, accx[1]); accy[1] = fmaf(w1, c1, accy[1]);
        accx[2] = fmaf(w2, c0, accx[2]); accy[2] = fmaf(w2, c1, accy[2]);
        accx[3] = fmaf(w3, c0, accx[3]); accy[3] = fmaf(w3, c1, accy[3]);
    }
}

template<int L>
__global__ __launch_bounds__(256) void aggregate_kernel(
    const int* __restrict__ rowptr, const int* __restrict__ colsrc,
    const char* __restrict__ pay, const float* __restrict__ asrc,
    const float* __restrict__ adst, char* __restrict__ gout, int N)
{
    int tid = threadIdx.x;
    int grp = tid >> 5;
    int lane32 = tid & 31;
    int n = blockIdx.x * 8 + grp;
    if (n >= N) return;
    int start = rowptr[n], end = rowptr[n + 1];
    int deg = end - start;
    const float4 ad = *(const float4*)(adst + (size_t)n * 4);

    int src0 = 0;
    float e0 = -1e30f, e1 = -1e30f, e2 = -1e30f, e3 = -1e30f;
    bool v0 = lane32 < deg;
    if (v0){
        src0 = colsrc[start + lane32];
        float4 as = *(const float4*)(asrc + (size_t)src0 * 4);
        e0 = leaky(as.x + ad.x); e1 = leaky(as.y + ad.y);
        e2 = leaky(as.z + ad.z); e3 = leaky(as.w + ad.w);
    }

    float m0, m1, m2, m3, i0, i1, i2, i3, p0, p1, p2, p3;
    if (deg <= 32){
        m0 = e0; m1 = e1; m2 = e2; m3 = e3;
        #pragma unroll
        for (int off = 1; off < 32; off <<= 1){
            m0 = fmaxf(m0, __shfl_xor(m0, off));
            m1 = fmaxf(m1, __shfl_xor(m1, off));
            m2 = fmaxf(m2, __shfl_xor(m2, off));
            m3 = fmaxf(m3, __shfl_xor(m3, off));
        }
        p0 = __expf(e0 - m0);
        p1 = __expf(e1 - m1);
        p2 = __expf(e2 - m2);
        p3 = __expf(e3 - m3);
        float t0 = p0, t1 = p1, t2 = p2, t3 = p3;
        #pragma unroll
        for (int off = 1; off < 32; off <<= 1){
            t0 += __shfl_xor(t0, off);
            t1 += __shfl_xor(t1, off);
            t2 += __shfl_xor(t2, off);
            t3 += __shfl_xor(t3, off);
        }
        i0 = 1.f / t0; i1 = 1.f / t1; i2 = 1.f / t2; i3 = 1.f / t3;
    } else {
        m0 = e0; m1 = e1; m2 = e2; m3 = e3;
        float t0 = v0 ? 1.f : 0.f, t1 = t0, t2 = t0, t3 = t0;
        for (int i = start + 32 + lane32; i < end; i += 32){
            int s = colsrc[i];
            float4 as = *(const float4*)(asrc + (size_t)s * 4);
            float e, nm;
            e = leaky(as.x + ad.x); nm = fmaxf(m0, e); t0 = t0 * __expf(m0 - nm) + __expf(e - nm); m0 = nm;
            e = leaky(as.y + ad.y); nm = fmaxf(m1, e); t1 = t1 * __expf(m1 - nm) + __expf(e - nm); m1 = nm;
            e = leaky(as.z + ad.z); nm = fmaxf(m2, e); t2 = t2 * __expf(m2 - nm) + __expf(e - nm); m2 = nm;
            e = leaky(as.w + ad.w); nm = fmaxf(m3, e); t3 = t3 * __expf(m3 - nm) + __expf(e - nm); m3 = nm;
        }
        #pragma unroll
        for (int off = 1; off < 32; off <<= 1){
            float om, os, nm;
            om = __shfl_xor(m0, off); os = __shfl_xor(t0, off);
            nm = fmaxf(m0, om); t0 = t0 * __expf(m0 - nm) + os * __expf(om - nm); m0 = nm;
            om = __shfl_xor(m1, off); os = __shfl_xor(t1, off);
            nm = fmaxf(m1, om); t1 = t1 * __expf(m1 - nm) + os * __expf(om - nm); m1 = nm;
            om = __shfl_xor(m2, off); os = __shfl_xor(t2, off);
            nm = fmaxf(m2, om); t2 = t2 * __expf(m2 - nm) + os * __expf(om - nm); m2 = nm;
            om = __shfl_xor(m3, off); os = __shfl_xor(t3, off);
            nm = fmaxf(m3, om); t3 = t3 * __expf(m3 - nm) + os * __expf(om - nm); m3 = nm;
        }
        i0 = 1.f / t0; i1 = 1.f / t1; i2 = 1.f / t2; i3 = 1.f / t3;
        p0 = __expf(e0 - m0); p1 = __expf(e1 - m1);
        p2 = __expf(e2 - m2); p3 = __expf(e3 - m3);
    }

    float accx[4] = {0.f, 0.f, 0.f, 0.f};
    float accy[4] = {0.f, 0.f, 0.f, 0.f};
    const int boff = lane32 * 4;
    bool first = true;
    for (int base = start; base < end; base += 32){
        int cnt = end - base; if (cnt > 32) cnt = 32;
        float w0, w1, w2, w3; int off = 0;
        if (first){
            w0 = p0 * i0; w1 = p1 * i1; w2 = p2 * i2; w3 = p3 * i3;
            off = v0 ? src0 * 128 : 0;
        } else {
            w0 = w1 = w2 = w3 = 0.f;
            if (lane32 < cnt){
                int s = colsrc[base + lane32];
                float4 as = *(const float4*)(asrc + (size_t)s * 4);
                w0 = __expf(leaky(as.x + ad.x) - m0) * i0;
                w1 = __expf(leaky(as.y + ad.y) - m1) * i1;
                w2 = __expf(leaky(as.z + ad.z) - m2) * i2;
                w3 = __expf(leaky(as.w + ad.w) - m3) * i3;
                off = s * 128;
            }
        }
        first = false;
        half2_t q01 = __builtin_amdgcn_cvt_pkrtz(w0, w1);
        half2_t q23 = __builtin_amdgcn_cvt_pkrtz(w2, w3);
        int wx = (int)__builtin_bit_cast(unsigned, q01);
        int wy = (int)__builtin_bit_cast(unsigned, q23);

        int j = 0;
        for (; j + 2 <= cnt; j += 2){
            int o0 = __shfl(off, j, 32);
            unsigned a0 = (unsigned)__shfl(wx, j, 32), b0 = (unsigned)__shfl(wy, j, 32);
            int o1 = __shfl(off, j + 1, 32);
            unsigned a1 = (unsigned)__shfl(wx, j + 1, 32), b1 = (unsigned)__shfl(wy, j + 1, 32);
            agg_edge<L>(pay, boff, o0, a0, b0, accx, accy);
            agg_edge<L>(pay, boff, o1, a1, b1, accx, accy);
        }
        for (; j < cnt; ++j){
            int o0 = __shfl(off, j, 32);
            unsigned a0 = (unsigned)__shfl(wx, j, 32), b0 = (unsigned)__shfl(wy, j, 32);
            agg_edge<L>(pay, boff, o0, a0, b0, accx, accy);
        }
    }

    if (L == 1){
        float* g = (float*)gout;
        #pragma unroll
        for (int h = 0; h < 4; ++h)
            g[(size_t)n * 128 + h * 32 + lane32] = accx[h];
    } else {
        #pragma unroll
        for (int h = 0; h < 4; ++h){
            unsigned u = packh2(accx[h], accy[h]);
            *(unsigned*)(gout + (size_t)n * 512 + h * 128 + lane32 * 4) = u;
        }
    }
}

// ---------------- t1post: hmid = elu(G1 @ W1p + b1), + layer-2 alphas ----------------
// G1 f32 [N][128] DIRECT reads; B = w1p bf16 staged in LDS (17.4KB); bf16x2 A split.
// Epilogue: hmid fp16 store + asrc2/adst2 = hmid . hat2 (f32, via quad shfl reduce).

__global__ __launch_bounds__(256) void t1post_kernel(
    const float* __restrict__ G1, const short* __restrict__ w1p, const float* __restrict__ b1,
    const float* __restrict__ hat2s, const float* __restrict__ hat2d,
    __half* __restrict__ hm16, float* __restrict__ asrc, float* __restrict__ adst, int N)
{
    constexpr int WP = 136;
    __shared__ short wt[64 * WP];
    const int tid = threadIdx.x;
    const int n0 = blockIdx.x * 64;
    const int wv = tid >> 6, lane = tid & 63;
    const int quad = lane >> 4, ln = lane & 15;
    const int myrow = wv * 16 + ln;
    const int nme = n0 + myrow;

    {
        const short8* g = (const short8*)w1p;
        short8* l = (short8*)wt;
        for (int t = tid; t < 64 * WP / 8; t += 256) l[t] = g[t];
    }
    __syncthreads();

    f32x4 acc[4];
    #pragma unroll
    for (int i = 0; i < 4; ++i) acc[i] = (f32x4){0.f, 0.f, 0.f, 0.f};

    #pragma unroll
    for (int ks = 0; ks < 4; ++ks){
        const int k0 = ks * 32 + quad * 8;
        float4 f0 = make_float4(0.f, 0.f, 0.f, 0.f), f1 = f0;
        if (nme < N){
            const float* ap = G1 + (size_t)nme * 128 + k0;
            f0 = *(const float4*)ap;
            f1 = *(const float4*)(ap + 4);
        }
        float fa[8] = {f0.x, f0.y, f0.z, f0.w, f1.x, f1.y, f1.z, f1.w};
        short8 ahi, alo;
        #pragma unroll
        for (int e = 0; e < 8; ++e){
            short hi = bf16_rne(fa[e]);
            ahi[e] = hi;
            alo[e] = bf16_rne(fa[e] - bf16_to_f(hi));
        }
        #pragma unroll
        for (int nt = 0; nt < 4; ++nt){
            short8 bhi = *(const short8*)(wt + (nt * 16 + ln) * WP + k0);
            acc[nt] = __builtin_amdgcn_mfma_f32_16x16x32_bf16(ahi, bhi, acc[nt], 0, 0, 0);
            acc[nt] = __builtin_amdgcn_mfma_f32_16x16x32_bf16(alo, bhi, acc[nt], 0, 0, 0);
        }
    }

    float b1v[4], hs[4][4], hd[4][4];
    #pragma unroll
    for (int nt = 0; nt < 4; ++nt) b1v[nt] = b1[nt * 16 + ln];
    #pragma unroll
    for (int h = 0; h < 4; ++h)
        #pragma unroll
        for (int nt = 0; nt < 4; ++nt){
            hs[h][nt] = hat2s[h * 64 + nt * 16 + ln];
            hd[h][nt] = hat2d[h * 64 + nt * 16 + ln];
        }

    #pragma unroll
    for (int r = 0; r < 4; ++r){
        int n = n0 + wv * 16 + quad * 4 + r;
        float ev[4];
        #pragma unroll
        for (int nt = 0; nt < 4; ++nt){
            float v = acc[nt][r] + b1v[nt];
            v = (v > 0.f) ? v : expm1f(v);
            ev[nt] = v;
        }
        if (n < N){
            #pragma unroll
            for (int nt = 0; nt < 4; ++nt)
                hm16[(size_t)n * 64 + nt * 16 + ln] = __float2half(ev[nt]);
        }
        #pragma unroll
        for (int h = 0; h < 4; ++h){
            float ps = 0.f, pd = 0.f;
            #pragma unroll
            for (int nt = 0; nt < 4; ++nt){
                ps = fmaf(ev[nt], hs[h][nt], ps);
                pd = fmaf(ev[nt], hd[h][nt], pd);
            }
            #pragma unroll
            for (int off = 1; off < 16; off <<= 1){
                ps += __shfl_xor(ps, off);
                pd += __shfl_xor(pd, off);
            }
            if (ln == 0 && n < N){
                asrc[n * 4 + h] = ps;
                adst[n * 4 + h] = pd;
            }
        }
    }
}

// ---------------- t2post: hmid2 = elu(G2 @ W2p + b2) ----------------
// G2 fp16 [N][256] DIRECT reads; B = w2p bf16 staged in LDS (33.8KB).

__global__ __launch_bounds__(256) void t2post_kernel(
    const char* __restrict__ G2, const short* __restrict__ w2p, const float* __restrict__ b2,
    float* __restrict__ hmid2, int N)
{
    constexpr int WP = 264;
    __shared__ short wt[64 * WP];
    const int tid = threadIdx.x;
    const int n0 = blockIdx.x * 64;
    const int wv = tid >> 6, lane = tid & 63;
    const int quad = lane >> 4, ln = lane & 15;
    const int myrow = wv * 16 + ln;
    const int nme = n0 + myrow;

    {
        const short8* g = (const short8*)w2p;
        short8* l = (short8*)wt;
        for (int t = tid; t < 64 * WP / 8; t += 256) l[t] = g[t];
    }
    __syncthreads();

    f32x4 acc[4];
    #pragma unroll
    for (int i = 0; i < 4; ++i) acc[i] = (f32x4){0.f, 0.f, 0.f, 0.f};

    #pragma unroll
    for (int ks = 0; ks < 8; ++ks){
        const int k0 = ks * 32 + quad * 8;
        uint4 u = make_uint4(0u, 0u, 0u, 0u);
        if (nme < N)
            u = *(const uint4*)(G2 + (size_t)nme * 512 + (size_t)k0 * 2);
        half2_t h0 = bc16(u.x), h1 = bc16(u.y), h2 = bc16(u.z), h3 = bc16(u.w);
        float fa[8] = {(float)h0[0], (float)h0[1], (float)h1[0], (float)h1[1],
                       (float)h2[0], (float)h2[1], (float)h3[0], (float)h3[1]};
        short8 ahi, alo;
        #pragma unroll
        for (int e = 0; e < 8; ++e){
            short hi = bf16_rne(fa[e]);
            ahi[e] = hi;
            alo[e] = bf16_rne(fa[e] - bf16_to_f(hi));
        }
        #pragma unroll
        for (int nt = 0; nt < 4; ++nt){
            short8 bhi = *(const short8*)(wt + (nt * 16 + ln) * WP + k0);
            acc[nt] = __builtin_amdgcn_mfma_f32_16x16x32_bf16(ahi, bhi, acc[nt], 0, 0, 0);
            acc[nt] = __builtin_amdgcn_mfma_f32_16x16x32_bf16(alo, bhi, acc[nt], 0, 0, 0);
        }
    }

    float b2v[4];
    #pragma unroll
    for (int nt = 0; nt < 4; ++nt) b2v[nt] = b2[nt * 16 + ln];
    #pragma unroll
    for (int r = 0; r < 4; ++r){
        int n = n0 + wv * 16 + quad * 4 + r;
        if (n < N){
            #pragma unroll
            for (int nt = 0; nt < 4; ++nt){
                float v = acc[nt][r] + b2v[nt];
                v = (v > 0.f) ? v : expm1f(v);
                hmid2[(size_t)n * 64 + nt * 16 + ln] = v;
            }
        }
    }
}

// ---------------- scorer: MFMA (bf16x3), DIRECT global A reads (unchanged) ----------------

__global__ __launch_bounds__(256) void scorer_mfma_kernel(
    const float* __restrict__ h2, const short* __restrict__ s1hi, const short* __restrict__ s1lo,
    const float* __restrict__ d1p, const float* __restrict__ Ws2, const float* __restrict__ bs2,
    float* __restrict__ out, int N)
{
    constexpr int WP = 72;
    __shared__ short whi[64 * WP];
    __shared__ short wlo[64 * WP];
    const int tid = threadIdx.x;
    const int n0 = blockIdx.x * 64;

    const int wv = tid >> 6, lane = tid & 63;
    const int quad = lane >> 4, ln = lane & 15;
    const int myrow = wv * 16 + ln;
    const int nme = n0 + myrow;

    float fdir[16];
    #pragma unroll
    for (int ks = 0; ks < 2; ++ks){
        float4 f0 = make_float4(0.f, 0.f, 0.f, 0.f), f1 = f0;
        if (nme < N){
            const float* ap = h2 + (size_t)nme * 64 + ks * 32 + quad * 8;
            f0 = *(const float4*)ap;
            f1 = *(const float4*)(ap + 4);
        }
        fdir[ks*8+0]=f0.x; fdir[ks*8+1]=f0.y; fdir[ks*8+2]=f0.z; fdir[ks*8+3]=f0.w;
        fdir[ks*8+4]=f1.x; fdir[ks*8+5]=f1.y; fdir[ks*8+6]=f1.z; fdir[ks*8+7]=f1.w;
    }
    {
        const short8* ghi = (const short8*)s1hi;
        const short8* glo = (const short8*)s1lo;
        short8* lhi = (short8*)whi;
        short8* llo = (short8*)wlo;
        for (int t = tid; t < 64 * WP / 8; t += 256){ lhi[t] = ghi[t]; llo[t] = glo[t]; }
    }
    __syncthreads();

    f32x4 acc[4];
    #pragma unroll
    for (int i = 0; i < 4; ++i) acc[i] = (f32x4){0.f, 0.f, 0.f, 0.f};

    #pragma unroll
    for (int ks = 0; ks < 2; ++ks) {
        const int k0 = ks * 32 + quad * 8;
        short8 ahi, alo;
        #pragma unroll
        for (int e = 0; e < 8; ++e) {
            float v = fdir[ks * 8 + e];
            short hi = bf16_rne(v);
            ahi[e] = hi;
            alo[e] = bf16_rne(v - bf16_to_f(hi));
        }
        #pragma unroll
        for (int nt = 0; nt < 4; ++nt) {
            short8 bhi = *(const short8*)(whi + (nt * 16 + ln) * WP + k0);
            short8 blo = *(const short8*)(wlo + (nt * 16 + ln) * WP + k0);
            acc[nt] = __builtin_amdgcn_mfma_f32_16x16x32_bf16(ahi, bhi, acc[nt], 0, 0, 0);
            acc[nt] = __builtin_amdgcn_mfma_f32_16x16x32_bf16(alo, bhi, acc[nt], 0, 0, 0);
            acc[nt] = __builtin_amdgcn_mfma_f32_16x16x32_bf16(ahi, blo, acc[nt], 0, 0, 0);
        }
    }

    float d1v[4], w2v[4];
    #pragma unroll
    for (int nt = 0; nt < 4; ++nt){
        d1v[nt] = d1p[nt * 16 + ln];
        w2v[nt] = Ws2[nt * 16 + ln];
    }
    float b2 = bs2[0];
    #pragma unroll
    for (int r = 0; r < 4; ++r){
        float t = 0.f;
        #pragma unroll
        for (int nt = 0; nt < 4; ++nt)
            t = fmaf(fmaxf(acc[nt][r] + d1v[nt], 0.f), w2v[nt], t);
        #pragma unroll
        for (int off = 1; off < 16; off <<= 1) t += __shfl_xor(t, off);
        if (ln == 0){
            int n = n0 + wv * 16 + quad * 4 + r;
            if (n < N) out[n] = t + b2;
        }
    }
}

// ---------------- launch ----------------

extern "C" void kernel_launch(void* const* d_in, const int* in_sizes, int n_in,
                              void* d_out, int out_size, void* d_ws, size_t ws_size,
                              hipStream_t stream)
{
    const float* x    = (const float*)d_in[0];
    const int*   ei   = (const int*)  d_in[1];
    const float* donor= (const float*)d_in[2];
    const float* W1   = (const float*)d_in[3];
    const float* as1  = (const float*)d_in[4];
    const float* ad1  = (const float*)d_in[5];
    const float* b1   = (const float*)d_in[6];
    const float* W2   = (const float*)d_in[7];
    const float* as2  = (const float*)d_in[8];
    const float* ad2  = (const float*)d_in[9];
    const float* b2   = (const float*)d_in[10];
    const float* Ws1  = (const float*)d_in[11];
    const float* bs1  = (const float*)d_in[12];
    const float* Ws2  = (const float*)d_in[13];
    const float* bs2  = (const float*)d_in[14];

    const int N  = in_sizes[0] / 27;
    const int E  = in_sizes[1] / 2;
    const int ET = E + N;
    const int NB = (N + 255) / 256;

    char* ws = (char*)d_ws;
    auto alloc = [&](size_t bytes) -> void* {
        void* p = (void*)ws;
        ws += (bytes + 255) / 256 * 256;
        return p;
    };
    int*      rowptr  = (int*)     alloc((size_t)(N + 1) * 4);
    int*      colsrc  = (int*)     alloc((size_t)ET * 4);
    unsigned* pairs   = (unsigned*)alloc((size_t)ET * 4);
    float*    xp      = (float*)   alloc((size_t)N * 128);        // [N][32] f32
    char*     gbuf    = (char*)    alloc((size_t)N * 512);        // G1 f32[N][128] / G2 fp16[N][256]
    __half*   hm16    = (__half*)  alloc((size_t)N * 128);        // [N][64] fp16
    float*    hmid2   = (float*)   alloc((size_t)N * 256);        // [N][64] f32
    float*    asrc    = (float*)   alloc((size_t)N * 4 * 4);
    float*    adst    = (float*)   alloc((size_t)N * 4 * 4);
    int*      bucket_cnt    = (int*) alloc(256 * 4);
    int*      bucket_cursor = (int*) alloc(256 * 4);   // contiguous with bucket_cnt
    short*    w1p     = (short*)   alloc(64 * 136 * 2);
    short*    w2p     = (short*)   alloc(64 * 264 * 2);
    short*    s1hi    = (short*)   alloc(64 * 72 * 2);
    short*    s1lo    = (short*)   alloc(64 * 72 * 2);
    float*    d1p     = (float*)   alloc(64 * 4);
    float*    hat1s   = (float*)   alloc(128 * 4);
    float*    hat1d   = (float*)   alloc(128 * 4);
    float*    hat2s   = (float*)   alloc(256 * 4);
    float*    hat2d   = (float*)   alloc(256 * 4);

    const int nblk = (N + 63) / 64;
    const int hblk = (ET + 2047) / 2048;
    const int XB   = 512;

    (void)hipMemsetAsync(bucket_cnt, 0, 512 * 4, stream);
    prep_hist_kernel<<<256 + hblk, 256, 0, stream>>>(
        W1, W2, Ws1, bs1, donor, as1, ad1, as2, ad2,
        w1p, w2p, s1hi, s1lo, d1p, hat1s, hat1d, hat2s, hat2d,
        ei, E, N, NB, bucket_cnt);
    coarse_scatter_kernel<<<hblk, 256, 0, stream>>>(ei, E, N, NB, bucket_cnt, bucket_cursor, pairs);
    xprep_fine_kernel<<<XB + NB, 256, 0, stream>>>(
        x, hat1s, hat1d, xp, asrc, adst, N,
        XB, pairs, bucket_cnt, NB, colsrc, rowptr, ET);
    aggregate_kernel<1><<<(N + 7) / 8, 256, 0, stream>>>(
        rowptr, colsrc, (const char*)xp, asrc, adst, gbuf, N);
    t1post_kernel<<<nblk, 256, 0, stream>>>(
        (const float*)gbuf, w1p, b1, hat2s, hat2d, hm16, asrc, adst, N);
    aggregate_kernel<2><<<(N + 7) / 8, 256, 0, stream>>>(
        rowptr, colsrc, (const char*)hm16, asrc, adst, gbuf, N);
    t2post_kernel<<<nblk, 256, 0, stream>>>(
        (const char*)gbuf, w2p, b2, hmid2, N);
    scorer_mfma_kernel<<<nblk, 256, 0, stream>>>(
        hmid2, s1hi, s1lo, d1p, Ws2, bs2, (float*)d_out, N);
}